// Round 9
// baseline (146.104 us; speedup 1.0000x reference)
//
#include <hip/hip_runtime.h>
#include <stdint.h>

#define BB 64
#define LL 512
#define DD 300
#define CC 128

// ws layout (floats):
//   Gpart : [64][32][3][300] = 1,843,200   (non-atomic per-half-block partials)
//   hT    : [64][384]        =    24,576   (b-major so k_fc reads coalesce)
#define OFF_HT (BB * 32 * 3 * DD)

// ---------------------------------------------------------------------------
// Kernel 1 (= R7's equal-best gather): weighted embedding gather, 8-deep
// explicit load batching.
//   Gpart[b][p][kk][d] = sum_{t in half-block p} u_k[t] * embed[x[b,t]][d]
// u_k[t] = sum of wk[l] over valid windows covering token t (<=5 terms).
// Grid 1024 x 256 (64 b x 16 tc; 32 tokens/block, 16 per half-block).
// Thread owns float2 slots {stid, 128+stid (tail, <150)} of each row; the 8
// row loads per batch are issued into register arrays before any FMA so each
// wave keeps 16 loads in flight (hides the ~900-cyc cold-HBM row latency).
// ---------------------------------------------------------------------------
__global__ __launch_bounds__(256) void k_gather(
    const int* __restrict__ x, const float* __restrict__ embed,
    const float* __restrict__ w3, const float* __restrict__ w4,
    const float* __restrict__ w5, float* __restrict__ Gpart) {
  const int b = blockIdx.x >> 4;
  const int tc = blockIdx.x & 15;
  const int tid = threadIdx.x;
  const int sub = tid >> 7;    // half-block: 16 tokens each
  const int stid = tid & 127;  // float2 slot

  __shared__ int sx[32];
  __shared__ float su[3][32];

  if (tid < 32) {
    const int t = tc * 32 + tid;
    sx[tid] = x[b * LL + t];
    const float* ws[3] = {w3, w4, w5};
#pragma unroll
    for (int kk = 0; kk < 3; ++kk) {
      const int k = kk + 3;
      int lo = t - k + 1; if (lo < 0) lo = 0;
      int hi = t; const int lim = LL - k - 1; if (hi > lim) hi = lim;
      float s = 0.f;
      for (int l = lo; l <= hi; ++l) s += ws[kk][l];
      su[kk][tid] = s;
    }
  }
  __syncthreads();

  float a0x = 0.f, a0y = 0.f, a1x = 0.f, a1y = 0.f, a2x = 0.f, a2y = 0.f;
  float c0x = 0.f, c0y = 0.f, c1x = 0.f, c1y = 0.f, c2x = 0.f, c2y = 0.f;
  const bool tail = stid < (DD / 2 - 128);  // slots 128..149 -> 22 lanes

#pragma unroll
  for (int half = 0; half < 2; ++half) {
    const int base = sub * 16 + half * 8;
    float2 v[8], u[8];
#pragma unroll
    for (int i = 0; i < 8; ++i) {
      const float2* rp = (const float2*)(embed + (size_t)sx[base + i] * DD);
      v[i] = rp[stid];
    }
    if (tail) {
#pragma unroll
      for (int i = 0; i < 8; ++i) {
        const float2* rp = (const float2*)(embed + (size_t)sx[base + i] * DD);
        u[i] = rp[128 + stid];
      }
    }
#pragma unroll
    for (int i = 0; i < 8; ++i) {
      const int j = base + i;
      const float w0 = su[0][j], w1 = su[1][j], w2 = su[2][j];
      a0x += w0 * v[i].x; a0y += w0 * v[i].y;
      a1x += w1 * v[i].x; a1y += w1 * v[i].y;
      a2x += w2 * v[i].x; a2y += w2 * v[i].y;
      if (tail) {
        c0x += w0 * u[i].x; c0y += w0 * u[i].y;
        c1x += w1 * u[i].x; c1y += w1 * u[i].y;
        c2x += w2 * u[i].x; c2y += w2 * u[i].y;
      }
    }
  }

  const int p = tc * 2 + sub;  // 0..31
  float* Gp = Gpart + (size_t)(b * 32 + p) * (3 * DD);
  const int d0 = 2 * stid;
  Gp[0 * DD + d0] = a0x; Gp[0 * DD + d0 + 1] = a0y;
  Gp[1 * DD + d0] = a1x; Gp[1 * DD + d0 + 1] = a1y;
  Gp[2 * DD + d0] = a2x; Gp[2 * DD + d0 + 1] = a2y;
  if (tail) {
    const int d1 = 2 * (128 + stid);
    Gp[0 * DD + d1] = c0x; Gp[0 * DD + d1 + 1] = c0y;
    Gp[1 * DD + d1] = c1x; Gp[1 * DD + d1 + 1] = c1y;
    Gp[2 * DD + d1] = c2x; Gp[2 * DD + d1 + 1] = c2y;
  }
}

// ---------------------------------------------------------------------------
// Kernel 2: fused partial-reduce + sim GEMV (replaces R8's k_reduce + k_sim;
// tests the ~5 us/graph-node overhead hypothesis by cutting a node).
// One block per (b,kk) = 192 blocks x 256.
//  - Reduce: sub s (128 thr) sums partials p = s*16..s*16+15 of
//    Gpart[b][p][kk][*] into sGh[s][*] (float2 slots {stid, 128+stid<150},
//    two 8-deep load batches — Gpart is L2-resident, 14.7 MB).
//  - Sk = sum(wk) computed in-block (64x redundant, ~2 loads/thread).
//  - Sim: 4 waves x 32 outputs cp; dot of conv_w[cp] (coalesced L2) against
//    sGh[0]+sGh[1] (LDS), 6-shfl reduce.
//   hT[b*384 + kk*128 + cp] = dot + conv_b[cp]*Sk + bk
// ---------------------------------------------------------------------------
__global__ __launch_bounds__(256) void k_redsim(
    const float* __restrict__ Gpart, const float* __restrict__ conv_w,
    const float* __restrict__ conv_b,
    const float* __restrict__ w3, const float* __restrict__ b3,
    const float* __restrict__ w4, const float* __restrict__ b4,
    const float* __restrict__ w5, const float* __restrict__ b5,
    float* __restrict__ hT) {
  const int blk = blockIdx.x;  // 192 = 64 b * 3 kk
  const int b = blk / 3;
  const int kk = blk - b * 3;
  const int tid = threadIdx.x;
  const int sub = tid >> 7;
  const int stid = tid & 127;

  __shared__ float2 sGh[2][150];
  __shared__ float red[256];

  // --- partial reduce (16 partials per sub, two 8-deep batches) ---
  {
    const float2* base =
        (const float2*)Gpart + ((size_t)(b * 32 + sub * 16) * 3 + kk) * 150;
    const bool tail = stid < 22;
    float2 acc0 = {0.f, 0.f}, acc1 = {0.f, 0.f};
#pragma unroll
    for (int half = 0; half < 2; ++half) {
      float2 v[8], u[8];
#pragma unroll
      for (int i = 0; i < 8; ++i)
        v[i] = base[(size_t)(half * 8 + i) * 450 + stid];
      if (tail) {
#pragma unroll
        for (int i = 0; i < 8; ++i)
          u[i] = base[(size_t)(half * 8 + i) * 450 + 128 + stid];
      }
#pragma unroll
      for (int i = 0; i < 8; ++i) {
        acc0.x += v[i].x; acc0.y += v[i].y;
        if (tail) { acc1.x += u[i].x; acc1.y += u[i].y; }
      }
    }
    sGh[sub][stid] = acc0;
    if (tail) sGh[sub][128 + stid] = acc1;
  }

  // --- Sk (in-block, redundant across the 64 b's — trivial) ---
  const float* wk = (kk == 0) ? w3 : ((kk == 1) ? w4 : w5);
  const float* bk = (kk == 0) ? b3 : ((kk == 1) ? b4 : b5);
  {
    const int len = LL - (kk + 3);
    float s = (tid < len) ? wk[tid] : 0.f;
    if (tid + 256 < len) s += wk[tid + 256];
    red[tid] = s;
  }
  __syncthreads();
  for (int off = 128; off >= 1; off >>= 1) {
    if (tid < off) red[tid] += red[tid + off];
    __syncthreads();
  }
  const float Sk = red[0];
  const float bkv = bk[0];

  // --- sim: 4 waves x 32 outputs ---
  const int lane = tid & 63;
  const int wid = tid >> 6;
  for (int m = 0; m < 32; ++m) {
    const int cp = wid * 32 + m;
    const float2* cwp = (const float2*)(conv_w + cp * DD);  // 150 float2
    float acc;
    {
      const float2 v = cwp[lane];
      const float2 g0 = sGh[0][lane], g1 = sGh[1][lane];
      acc = v.x * (g0.x + g1.x) + v.y * (g0.y + g1.y);
    }
    {
      const float2 v = cwp[lane + 64];
      const float2 g0 = sGh[0][lane + 64], g1 = sGh[1][lane + 64];
      acc += v.x * (g0.x + g1.x) + v.y * (g0.y + g1.y);
    }
    if (lane < 22) {
      const float2 v = cwp[lane + 128];
      const float2 g0 = sGh[0][lane + 128], g1 = sGh[1][lane + 128];
      acc += v.x * (g0.x + g1.x) + v.y * (g0.y + g1.y);
    }
#pragma unroll
    for (int off = 32; off >= 1; off >>= 1) acc += __shfl_down(acc, off, 64);
    if (lane == 0) {
      hT[b * (3 * CC) + kk * CC + cp] = acc + conv_b[cp] * Sk + bkv;
    }
  }
}

// ---------------------------------------------------------------------------
// Kernel 3: final FC — one wave per output o = b*128 + c  (8192 outputs).
// Grid 2048 x 256. hT is [b][j]-major and fcw rows are j-major, so both
// reads coalesce across lanes (6 segments of 64).
//   out[b,c] = sum_j fcw[c,j]*hT[b,j] + fcb[c]
// ---------------------------------------------------------------------------
__global__ __launch_bounds__(256) void k_fc(
    const float* __restrict__ hT, const float* __restrict__ fcw,
    const float* __restrict__ fcb, float* __restrict__ out) {
  const int o = blockIdx.x * 4 + (threadIdx.x >> 6);
  const int lane = threadIdx.x & 63;
  const int b = o >> 7;
  const int c = o & 127;

  const float* fr = fcw + c * (3 * CC);
  const float* hr = hT + b * (3 * CC);
  float acc = 0.f;
#pragma unroll
  for (int s = 0; s < 6; ++s) acc += fr[s * 64 + lane] * hr[s * 64 + lane];
#pragma unroll
  for (int off = 32; off >= 1; off >>= 1) acc += __shfl_down(acc, off, 64);
  if (lane == 0) out[b * CC + c] = acc + fcb[c];
}

// ---------------------------------------------------------------------------
extern "C" void kernel_launch(void* const* d_in, const int* in_sizes, int n_in,
                              void* d_out, int out_size, void* d_ws,
                              size_t ws_size, hipStream_t stream) {
  const int* x = (const int*)d_in[0];
  const float* embed = (const float*)d_in[1];
  const float* conv_w = (const float*)d_in[2];
  const float* conv_b = (const float*)d_in[3];
  const float* fc3w = (const float*)d_in[4];
  const float* fc3b = (const float*)d_in[5];
  const float* fc4w = (const float*)d_in[6];
  const float* fc4b = (const float*)d_in[7];
  const float* fc5w = (const float*)d_in[8];
  const float* fc5b = (const float*)d_in[9];
  const float* fcw = (const float*)d_in[10];
  const float* fcb = (const float*)d_in[11];

  float* Gpart = (float*)d_ws;
  float* hT = (float*)d_ws + OFF_HT;

  k_gather<<<dim3(BB * 16), dim3(256), 0, stream>>>(x, embed, fc3w, fc4w,
                                                    fc5w, Gpart);
  k_redsim<<<dim3(BB * 3), dim3(256), 0, stream>>>(
      Gpart, conv_w, conv_b, fc3w, fc3b, fc4w, fc4b, fc5w, fc5b, hT);
  k_fc<<<dim3(2048), dim3(256), 0, stream>>>(hT, fcw, fcb, (float*)d_out);
}

// Round 10
// 137.909 us; speedup vs baseline: 1.0594x; 1.0594x over previous
//
#include <hip/hip_runtime.h>
#include <stdint.h>

#define BB 64
#define LL 512
#define DD 300
#define CC 128

// ws layout (floats):
//   Gpart : [64][32][3][300] = 1,843,200   (non-atomic per-half-block partials)
//   hT    : [64][384]        =    24,576   (b-major so k_fc reads coalesce)
#define OFF_HT (BB * 32 * 3 * DD)

// ---------------------------------------------------------------------------
// Kernel 1 (= R7's best gather): weighted embedding gather, 8-deep explicit
// load batching.
//   Gpart[b][p][kk][d] = sum_{t in half-block p} u_k[t] * embed[x[b,t]][d]
// u_k[t] = sum of wk[l] over valid windows covering token t (<=5 terms).
// Grid 1024 x 256 (64 b x 16 tc; 32 tokens/block, 16 per half-block).
// 16 waves/CU x 16 outstanding 512B row-loads/wave ≈ latency-BW product
// (R8 showed 2x blocks is neutral — already saturated).
// ---------------------------------------------------------------------------
__global__ __launch_bounds__(256) void k_gather(
    const int* __restrict__ x, const float* __restrict__ embed,
    const float* __restrict__ w3, const float* __restrict__ w4,
    const float* __restrict__ w5, float* __restrict__ Gpart) {
  const int b = blockIdx.x >> 4;
  const int tc = blockIdx.x & 15;
  const int tid = threadIdx.x;
  const int sub = tid >> 7;    // half-block: 16 tokens each
  const int stid = tid & 127;  // float2 slot

  __shared__ int sx[32];
  __shared__ float su[3][32];

  if (tid < 32) {
    const int t = tc * 32 + tid;
    sx[tid] = x[b * LL + t];
    const float* ws[3] = {w3, w4, w5};
#pragma unroll
    for (int kk = 0; kk < 3; ++kk) {
      const int k = kk + 3;
      int lo = t - k + 1; if (lo < 0) lo = 0;
      int hi = t; const int lim = LL - k - 1; if (hi > lim) hi = lim;
      float s = 0.f;
      for (int l = lo; l <= hi; ++l) s += ws[kk][l];
      su[kk][tid] = s;
    }
  }
  __syncthreads();

  float a0x = 0.f, a0y = 0.f, a1x = 0.f, a1y = 0.f, a2x = 0.f, a2y = 0.f;
  float c0x = 0.f, c0y = 0.f, c1x = 0.f, c1y = 0.f, c2x = 0.f, c2y = 0.f;
  const bool tail = stid < (DD / 2 - 128);  // slots 128..149 -> 22 lanes

#pragma unroll
  for (int half = 0; half < 2; ++half) {
    const int base = sub * 16 + half * 8;
    float2 v[8], u[8];
#pragma unroll
    for (int i = 0; i < 8; ++i) {
      const float2* rp = (const float2*)(embed + (size_t)sx[base + i] * DD);
      v[i] = rp[stid];
    }
    if (tail) {
#pragma unroll
      for (int i = 0; i < 8; ++i) {
        const float2* rp = (const float2*)(embed + (size_t)sx[base + i] * DD);
        u[i] = rp[128 + stid];
      }
    }
#pragma unroll
    for (int i = 0; i < 8; ++i) {
      const int j = base + i;
      const float w0 = su[0][j], w1 = su[1][j], w2 = su[2][j];
      a0x += w0 * v[i].x; a0y += w0 * v[i].y;
      a1x += w1 * v[i].x; a1y += w1 * v[i].y;
      a2x += w2 * v[i].x; a2y += w2 * v[i].y;
      if (tail) {
        c0x += w0 * u[i].x; c0y += w0 * u[i].y;
        c1x += w1 * u[i].x; c1y += w1 * u[i].y;
        c2x += w2 * u[i].x; c2y += w2 * u[i].y;
      }
    }
  }

  const int p = tc * 2 + sub;  // 0..31
  float* Gp = Gpart + (size_t)(b * 32 + p) * (3 * DD);
  const int d0 = 2 * stid;
  Gp[0 * DD + d0] = a0x; Gp[0 * DD + d0 + 1] = a0y;
  Gp[1 * DD + d0] = a1x; Gp[1 * DD + d0 + 1] = a1y;
  Gp[2 * DD + d0] = a2x; Gp[2 * DD + d0 + 1] = a2y;
  if (tail) {
    const int d1 = 2 * (128 + stid);
    Gp[0 * DD + d1] = c0x; Gp[0 * DD + d1 + 1] = c0y;
    Gp[1 * DD + d1] = c1x; Gp[1 * DD + d1 + 1] = c1y;
    Gp[2 * DD + d1] = c2x; Gp[2 * DD + d1 + 1] = c2y;
  }
}

// ---------------------------------------------------------------------------
// Kernel 2: fused reduce + sim, REDUNDANT-reduce variant (fixes R9's
// 192-block starvation: fusion must not cost occupancy).
// Grid 512 x 256 = (b, g in [0,8)); each block:
//  - redundantly reduces ALL 32 partials of its b into sG[900] (225 threads
//    x 32 float4, 8-deep batched; Gpart is L2-resident so the 4x read
//    amplification is ~59 MB of L2 traffic ≈ 2 us total),
//  - computes Sk[kk] via 3 wave-local reductions (no barrier trees),
//  - computes its 48 outputs j = g*48 .. g*48+47 (4 waves x 12).
//   hT[b*384 + j] = <conv_w[cp], sG[kk]> + conv_b[cp]*Sk[kk] + bk[kk]
// ---------------------------------------------------------------------------
__global__ __launch_bounds__(256) void k_redsim2(
    const float* __restrict__ Gpart, const float* __restrict__ conv_w,
    const float* __restrict__ conv_b,
    const float* __restrict__ w3, const float* __restrict__ b3,
    const float* __restrict__ w4, const float* __restrict__ b4,
    const float* __restrict__ w5, const float* __restrict__ b5,
    float* __restrict__ hT) {
  const int b = blockIdx.x >> 3;
  const int g = blockIdx.x & 7;
  const int tid = threadIdx.x;
  const int lane = tid & 63;
  const int wid = tid >> 6;

  __shared__ __align__(16) float sG[3 * DD];  // 900
  __shared__ float sSk[3], sbk[3];

  // --- redundant full reduce: 225 float4 slots x 32 partials ---
  if (tid < 225) {
    const float4* gp = (const float4*)Gpart + (size_t)b * 32 * 225 + tid;
    float4 acc = {0.f, 0.f, 0.f, 0.f};
#pragma unroll
    for (int p0 = 0; p0 < 32; p0 += 8) {
      float4 v[8];
#pragma unroll
      for (int i = 0; i < 8; ++i) v[i] = gp[(size_t)(p0 + i) * 225];
#pragma unroll
      for (int i = 0; i < 8; ++i) {
        acc.x += v[i].x; acc.y += v[i].y; acc.z += v[i].z; acc.w += v[i].w;
      }
    }
    ((float4*)sG)[tid] = acc;
  }

  // --- Sk via wave-local reductions (waves 0..2, concurrent with reduce) ---
  if (wid < 3) {
    const float* wk = (wid == 0) ? w3 : ((wid == 1) ? w4 : w5);
    const int len = LL - (wid + 3);
    float s = 0.f;
    for (int l = lane; l < len; l += 64) s += wk[l];
#pragma unroll
    for (int off = 32; off >= 1; off >>= 1) s += __shfl_down(s, off, 64);
    if (lane == 0) {
      sSk[wid] = s;
      sbk[wid] = (wid == 0) ? b3[0] : ((wid == 1) ? b4[0] : b5[0]);
    }
  }
  __syncthreads();

  // --- sim: 4 waves x 12 outputs ---
  const float2* sG2 = (const float2*)sG;
  const int j0 = g * 48 + wid * 12;
#pragma unroll 2
  for (int m = 0; m < 12; ++m) {
    const int j = j0 + m;
    const int kk = j >> 7;
    const int cp = j & 127;
    const float2* cwp = (const float2*)(conv_w + cp * DD);  // 150 float2
    const float2* g2 = sG2 + kk * 150;
    float acc;
    {
      const float2 v = cwp[lane];
      const float2 gg = g2[lane];
      acc = v.x * gg.x + v.y * gg.y;
    }
    {
      const float2 v = cwp[lane + 64];
      const float2 gg = g2[lane + 64];
      acc += v.x * gg.x + v.y * gg.y;
    }
    if (lane < 22) {
      const float2 v = cwp[lane + 128];
      const float2 gg = g2[lane + 128];
      acc += v.x * gg.x + v.y * gg.y;
    }
#pragma unroll
    for (int off = 32; off >= 1; off >>= 1) acc += __shfl_down(acc, off, 64);
    if (lane == 0) {
      hT[b * (3 * CC) + j] = acc + conv_b[cp] * sSk[kk] + sbk[kk];
    }
  }
}

// ---------------------------------------------------------------------------
// Kernel 3: final FC — one wave per output o = b*128 + c  (8192 outputs).
// Grid 2048 x 256. hT is [b][j]-major and fcw rows are j-major, so both
// reads coalesce across lanes (6 segments of 64).
//   out[b,c] = sum_j fcw[c,j]*hT[b,j] + fcb[c]
// ---------------------------------------------------------------------------
__global__ __launch_bounds__(256) void k_fc(
    const float* __restrict__ hT, const float* __restrict__ fcw,
    const float* __restrict__ fcb, float* __restrict__ out) {
  const int o = blockIdx.x * 4 + (threadIdx.x >> 6);
  const int lane = threadIdx.x & 63;
  const int b = o >> 7;
  const int c = o & 127;

  const float* fr = fcw + c * (3 * CC);
  const float* hr = hT + b * (3 * CC);
  float acc = 0.f;
#pragma unroll
  for (int s = 0; s < 6; ++s) acc += fr[s * 64 + lane] * hr[s * 64 + lane];
#pragma unroll
  for (int off = 32; off >= 1; off >>= 1) acc += __shfl_down(acc, off, 64);
  if (lane == 0) out[b * CC + c] = acc + fcb[c];
}

// ---------------------------------------------------------------------------
extern "C" void kernel_launch(void* const* d_in, const int* in_sizes, int n_in,
                              void* d_out, int out_size, void* d_ws,
                              size_t ws_size, hipStream_t stream) {
  const int* x = (const int*)d_in[0];
  const float* embed = (const float*)d_in[1];
  const float* conv_w = (const float*)d_in[2];
  const float* conv_b = (const float*)d_in[3];
  const float* fc3w = (const float*)d_in[4];
  const float* fc3b = (const float*)d_in[5];
  const float* fc4w = (const float*)d_in[6];
  const float* fc4b = (const float*)d_in[7];
  const float* fc5w = (const float*)d_in[8];
  const float* fc5b = (const float*)d_in[9];
  const float* fcw = (const float*)d_in[10];
  const float* fcb = (const float*)d_in[11];

  float* Gpart = (float*)d_ws;
  float* hT = (float*)d_ws + OFF_HT;

  k_gather<<<dim3(BB * 16), dim3(256), 0, stream>>>(x, embed, fc3w, fc4w,
                                                    fc5w, Gpart);
  k_redsim2<<<dim3(BB * 8), dim3(256), 0, stream>>>(
      Gpart, conv_w, conv_b, fc3w, fc3b, fc4w, fc4b, fc5w, fc5b, hT);
  k_fc<<<dim3(2048), dim3(256), 0, stream>>>(hT, fcw, fcb, (float*)d_out);
}

// Round 11
// 129.100 us; speedup vs baseline: 1.1317x; 1.0682x over previous
//
#include <hip/hip_runtime.h>
#include <stdint.h>

#define BB 64
#define LL 512
#define DD 300
#define CC 128

// ws layout (floats):
//   Gpart : [64][32][3][300] = 1,843,200  (non-atomic per-half-block partials)
//   Gred  : [64][900]        =    57,600  (float4 view: [64][225])
//   W2    : [128][900]       =   115,200  (fused sim∘fc weights)
//   bias2 : [128]
#define OFF_GRED  (BB * 32 * 3 * DD)
#define OFF_W2    (OFF_GRED + BB * 3 * DD)
#define OFF_BIAS2 (OFF_W2 + CC * 3 * DD)

// ---------------------------------------------------------------------------
// Kernel 1: gather + (independent) head-weight precompute, one grid.
// Blocks 0..1023   : R7's best gather — 8-deep batched row loads.
//   Gpart[b][p][kk][d] = sum_{t in half-block p} u_k[t] * embed[x[b,t]][d]
// Blocks 1024..1503: W2[c][kk*300+d] = sum_cp fcw[c,kk*128+cp]*conv_w[cp,d]
//   (1920 waves: one per (c,kk,64-d-chunk); fcw wave-uniform scalar loads,
//    conv_w coalesced; no dependency on gather — fills CUs under its HBM
//    latency.)
// Blocks 1504..1535: bias2[c] = sum_j fcw[c,j]*(cb[j&127]*Sk+bk) + fcb[c]
//   (wave per c; Sk computed in-wave.)
// ---------------------------------------------------------------------------
__global__ __launch_bounds__(256) void k_gather(
    const int* __restrict__ x, const float* __restrict__ embed,
    const float* __restrict__ conv_w, const float* __restrict__ conv_b,
    const float* __restrict__ w3, const float* __restrict__ b3,
    const float* __restrict__ w4, const float* __restrict__ b4,
    const float* __restrict__ w5, const float* __restrict__ b5,
    const float* __restrict__ fcw, const float* __restrict__ fcb,
    float* __restrict__ Gpart, float* __restrict__ W2,
    float* __restrict__ bias2) {
  const int blk = blockIdx.x;
  const int tid = threadIdx.x;

  if (blk < 1024) {  // ---------------- gather ----------------
    const int b = blk >> 4;
    const int tc = blk & 15;
    const int sub = tid >> 7;    // half-block: 16 tokens each
    const int stid = tid & 127;  // float2 slot

    __shared__ int sx[32];
    __shared__ float su[3][32];

    if (tid < 32) {
      const int t = tc * 32 + tid;
      sx[tid] = x[b * LL + t];
      const float* ws[3] = {w3, w4, w5};
#pragma unroll
      for (int kk = 0; kk < 3; ++kk) {
        const int k = kk + 3;
        int lo = t - k + 1; if (lo < 0) lo = 0;
        int hi = t; const int lim = LL - k - 1; if (hi > lim) hi = lim;
        float s = 0.f;
        for (int l = lo; l <= hi; ++l) s += ws[kk][l];
        su[kk][tid] = s;
      }
    }
    __syncthreads();

    float a0x = 0.f, a0y = 0.f, a1x = 0.f, a1y = 0.f, a2x = 0.f, a2y = 0.f;
    float c0x = 0.f, c0y = 0.f, c1x = 0.f, c1y = 0.f, c2x = 0.f, c2y = 0.f;
    const bool tail = stid < (DD / 2 - 128);  // slots 128..149 -> 22 lanes

#pragma unroll
    for (int half = 0; half < 2; ++half) {
      const int base = sub * 16 + half * 8;
      float2 v[8], u[8];
#pragma unroll
      for (int i = 0; i < 8; ++i) {
        const float2* rp = (const float2*)(embed + (size_t)sx[base + i] * DD);
        v[i] = rp[stid];
      }
      if (tail) {
#pragma unroll
        for (int i = 0; i < 8; ++i) {
          const float2* rp =
              (const float2*)(embed + (size_t)sx[base + i] * DD);
          u[i] = rp[128 + stid];
        }
      }
#pragma unroll
      for (int i = 0; i < 8; ++i) {
        const int j = base + i;
        const float w0 = su[0][j], w1 = su[1][j], w2 = su[2][j];
        a0x += w0 * v[i].x; a0y += w0 * v[i].y;
        a1x += w1 * v[i].x; a1y += w1 * v[i].y;
        a2x += w2 * v[i].x; a2y += w2 * v[i].y;
        if (tail) {
          c0x += w0 * u[i].x; c0y += w0 * u[i].y;
          c1x += w1 * u[i].x; c1y += w1 * u[i].y;
          c2x += w2 * u[i].x; c2y += w2 * u[i].y;
        }
      }
    }

    const int p = tc * 2 + sub;  // 0..31
    float* Gp = Gpart + (size_t)(b * 32 + p) * (3 * DD);
    const int d0 = 2 * stid;
    Gp[0 * DD + d0] = a0x; Gp[0 * DD + d0 + 1] = a0y;
    Gp[1 * DD + d0] = a1x; Gp[1 * DD + d0 + 1] = a1y;
    Gp[2 * DD + d0] = a2x; Gp[2 * DD + d0 + 1] = a2y;
    if (tail) {
      const int d1 = 2 * (128 + stid);
      Gp[0 * DD + d1] = c0x; Gp[0 * DD + d1 + 1] = c0y;
      Gp[1 * DD + d1] = c1x; Gp[1 * DD + d1 + 1] = c1y;
      Gp[2 * DD + d1] = c2x; Gp[2 * DD + d1 + 1] = c2y;
    }
  } else if (blk < 1504) {  // ---------------- W2 precompute ----------------
    const int w = (blk - 1024) * 4 + (tid >> 6);  // 0..1919
    const int lane = tid & 63;
    const int c = w / 15;
    const int rem = w - c * 15;
    const int kk = rem / 5;
    const int chunk = rem - kk * 5;
    const int d = chunk * 64 + lane;
    if (d < DD) {
      const float* fr = fcw + c * (3 * CC) + kk * CC;  // 128 wave-uniform
      float acc0 = 0.f, acc1 = 0.f;
#pragma unroll 4
      for (int cp = 0; cp < CC; cp += 2) {
        acc0 += fr[cp] * conv_w[cp * DD + d];
        acc1 += fr[cp + 1] * conv_w[(cp + 1) * DD + d];
      }
      W2[c * (3 * DD) + kk * DD + d] = acc0 + acc1;
    }
  } else {  // ---------------- bias2 ----------------
    const int wid = tid >> 6;
    const int lane = tid & 63;
    const int c = (blk - 1504) * 4 + wid;  // 0..127
    // in-wave Sk[3]
    float sk[3];
    const float* ws[3] = {w3, w4, w5};
#pragma unroll
    for (int kk = 0; kk < 3; ++kk) {
      const int len = LL - (kk + 3);
      float s = 0.f;
      for (int l = lane; l < len; l += 64) s += ws[kk][l];
#pragma unroll
      for (int off = 32; off >= 1; off >>= 1) s += __shfl_down(s, off, 64);
      sk[kk] = __shfl(s, 0, 64);
    }
    const float bkv[3] = {b3[0], b4[0], b5[0]};
    float acc = 0.f;
#pragma unroll
    for (int s6 = 0; s6 < 6; ++s6) {
      const int j = s6 * 64 + lane;
      const int kk = j >> 7;
      const int cp = j & 127;
      acc += fcw[c * (3 * CC) + j] * (conv_b[cp] * sk[kk] + bkv[kk]);
    }
#pragma unroll
    for (int off = 32; off >= 1; off >>= 1) acc += __shfl_down(acc, off, 64);
    if (lane == 0) bias2[c] = acc + fcb[c];
  }
}

// ---------------------------------------------------------------------------
// Kernel 2: parallel partial reduction (R7's, minus the Sk side-blocks).
// 14400 float4 outputs x 4 threads each (8 partials per thread, 2-step shfl
// combine) = 57600 threads in 225... -> 450 blocks of 128? Keep 256-thread
// blocks: 225 blocks of 256 handle gid<57600 with 4 thr/output.
// ---------------------------------------------------------------------------
__global__ __launch_bounds__(256) void k_reduce(
    const float* __restrict__ Gpart, float* __restrict__ Gred) {
  const int gid = blockIdx.x * 256 + threadIdx.x;  // < 57600
  const int out = gid >> 2;  // float4 output id, < 14400
  const int r = gid & 3;     // partial-group 0..3
  const int b = out / 225;
  const int q = out - b * 225;
  const float4* gp =
      (const float4*)Gpart + (size_t)b * 32 * 225 + (size_t)r * 8 * 225 + q;
  float4 s = gp[0];
#pragma unroll
  for (int p = 1; p < 8; ++p) {
    const float4 v = gp[(size_t)p * 225];
    s.x += v.x; s.y += v.y; s.z += v.z; s.w += v.w;
  }
#pragma unroll
  for (int off = 1; off <= 2; off <<= 1) {
    s.x += __shfl_down(s.x, off, 64);
    s.y += __shfl_down(s.y, off, 64);
    s.z += __shfl_down(s.z, off, 64);
    s.w += __shfl_down(s.w, off, 64);
  }
  if (r == 0) ((float4*)Gred)[out] = s;
}

// ---------------------------------------------------------------------------
// Kernel 3: fused head GEMV — one wave per output o = b*128 + c (8192).
// Grid 2048 x 256.  out[b,c] = <W2[c,:], Gred[b,:]> + bias2[c]
// (900-dot; W2 460 KB + Gred 230 KB both L2-resident, coalesced float2.)
// ---------------------------------------------------------------------------
__global__ __launch_bounds__(256) void k_out(
    const float* __restrict__ Gred, const float* __restrict__ W2,
    const float* __restrict__ bias2, float* __restrict__ out) {
  const int o = blockIdx.x * 4 + (threadIdx.x >> 6);
  const int lane = threadIdx.x & 63;
  const int b = o >> 7;
  const int c = o & 127;

  const float2* wr = (const float2*)(W2 + c * (3 * DD));   // 450 float2
  const float2* gr = (const float2*)(Gred + b * (3 * DD)); // 450 float2
  float acc = 0.f;
#pragma unroll
  for (int s = 0; s < 7; ++s) {
    const float2 v = wr[s * 64 + lane];
    const float2 g = gr[s * 64 + lane];
    acc += v.x * g.x + v.y * g.y;
  }
  if (lane < 2) {
    const float2 v = wr[448 + lane];
    const float2 g = gr[448 + lane];
    acc += v.x * g.x + v.y * g.y;
  }
#pragma unroll
  for (int off = 32; off >= 1; off >>= 1) acc += __shfl_down(acc, off, 64);
  if (lane == 0) out[b * CC + c] = acc + bias2[c];
}

// ---------------------------------------------------------------------------
extern "C" void kernel_launch(void* const* d_in, const int* in_sizes, int n_in,
                              void* d_out, int out_size, void* d_ws,
                              size_t ws_size, hipStream_t stream) {
  const int* x = (const int*)d_in[0];
  const float* embed = (const float*)d_in[1];
  const float* conv_w = (const float*)d_in[2];
  const float* conv_b = (const float*)d_in[3];
  const float* fc3w = (const float*)d_in[4];
  const float* fc3b = (const float*)d_in[5];
  const float* fc4w = (const float*)d_in[6];
  const float* fc4b = (const float*)d_in[7];
  const float* fc5w = (const float*)d_in[8];
  const float* fc5b = (const float*)d_in[9];
  const float* fcw = (const float*)d_in[10];
  const float* fcb = (const float*)d_in[11];

  float* Gpart = (float*)d_ws;
  float* Gred = (float*)d_ws + OFF_GRED;
  float* W2 = (float*)d_ws + OFF_W2;
  float* bias2 = (float*)d_ws + OFF_BIAS2;

  k_gather<<<dim3(1536), dim3(256), 0, stream>>>(
      x, embed, conv_w, conv_b, fc3w, fc3b, fc4w, fc4b, fc5w, fc5b, fcw, fcb,
      Gpart, W2, bias2);
  k_reduce<<<dim3(225), dim3(256), 0, stream>>>(Gpart, Gred);
  k_out<<<dim3(2048), dim3(256), 0, stream>>>(Gred, W2, bias2,
                                              (float*)d_out);
}